// Round 1
// baseline (750.056 us; speedup 1.0000x reference)
//
#include <hip/hip_runtime.h>
#include <stdint.h>

#define L_SEQ 512
#define BATCH 64
#define EDIM  256
#define HDIM  256
#define KTOT  512   // E + H
#define TDIM  50
#define HID2  512   // 2*H

typedef __attribute__((ext_vector_type(8))) short bf16x8;
typedef __attribute__((ext_vector_type(4))) short bf16x4;
typedef __attribute__((ext_vector_type(4))) float f32x4;

static __device__ __forceinline__ unsigned short f2bf(float f) {
  union { float f; unsigned int u; } v; v.f = f;
  unsigned int r = (v.u + 0x7FFFu + ((v.u >> 16) & 1u)) >> 16;  // RNE
  return (unsigned short)r;
}

static __device__ __forceinline__ bf16x8 pack8(const float* f) {
  bf16x8 r;
#pragma unroll
  for (int i = 0; i < 8; ++i) r[i] = (short)f2bf(f[i]);
  return r;
}

// LDS u-tile: [16 rows (batch m)][512 k] bf16, 1024 B/row,
// byte addr = m*1024 + ((k*2) ^ ((m&7)<<4))   (T2 XOR swizzle, 16B granular)

__global__ __launch_bounds__(512) void scan_kernel(
    const int* __restrict__ text, const float* __restrict__ emb,
    const float* __restrict__ W_f, const float* __restrict__ b_f,
    const float* __restrict__ W_b, const float* __restrict__ b_b,
    float* __restrict__ hidden /* [512][64][512] f32 */) {
  const int wg  = blockIdx.x;     // 0..7
  const int dir = wg >> 2;        // 0 = forward, 1 = backward
  const int b0  = (wg & 3) * 16;  // batch offset
  const int tid = threadIdx.x;
  const int w   = tid >> 6;       // wave 0..7, owns output tiles nt = 2w, 2w+1
  const int ln  = tid & 63;
  const int m16 = ln & 15;        // A-row / B-col / D-col index
  const int g4  = ln >> 4;        // 0..3

  const float* W    = dir ? W_b : W_f;
  const float* bias = dir ? b_b : b_f;

  __shared__ __align__(16) unsigned char uLds[16 * 1024];

  // ---- W fragments in registers: A-operand layout.
  // A[p][q] = W[16*nt + p][32*kk + q]; lane: p = m16, q = 8*g4 + i.
  bf16x8 wfrag[2][16];
#pragma unroll
  for (int t = 0; t < 2; ++t) {
    const int j0 = (2 * w + t) * 16 + m16;  // W row (output index)
#pragma unroll
    for (int kk = 0; kk < 16; ++kk) {
      const float* p = W + j0 * KTOT + kk * 32 + g4 * 8;
      float4 p0 = *(const float4*)(p);
      float4 p1 = *(const float4*)(p + 4);
      float f[8] = {p0.x, p0.y, p0.z, p0.w, p1.x, p1.y, p1.z, p1.w};
      wfrag[t][kk] = pack8(f);
    }
  }
  // bias per lane: D rows j = 32w + 16t + 4*g4 + r
  float biasr[2][4];
#pragma unroll
  for (int t = 0; t < 2; ++t)
#pragma unroll
    for (int r = 0; r < 4; ++r) biasr[t][r] = bias[32 * w + 16 * t + 4 * g4 + r];

  // ---- zero h region (bytes [512,1024) of each row; zeros are swizzle-invariant)
  {
    int m = tid >> 5;
    int off = m * 1024 + 512 + (tid & 31) * 16;
    *(f32x4*)(uLds + off) = f32x4{0.f, 0.f, 0.f, 0.f};
  }

  // ---- x prefetch: thread covers row m = tid>>5, elems e0..e0+7
  float4 xa, xb;
  const int xm = tid >> 5;
  const int e0 = (tid & 31) * 8;
  auto issue_x = [&](int step) {
    int srcl = dir ? (L_SEQ - 1 - step) : step;
    int tok = text[srcl * BATCH + b0 + xm];
    const float* p = emb + (long)tok * EDIM + e0;
    xa = *(const float4*)(p);
    xb = *(const float4*)(p + 4);
  };
  auto write_x = [&]() {
    float f[8] = {xa.x, xa.y, xa.z, xa.w, xb.x, xb.y, xb.z, xb.w};
    bf16x8 v = pack8(f);
    int off = xm * 1024 + ((e0 * 2) ^ ((xm & 7) << 4));
    *(bf16x8*)(uLds + off) = v;
  };
  issue_x(0);
  write_x();
  __syncthreads();

  // ---- main scan loop
  for (int step = 0; step < L_SEQ; ++step) {
    if (step + 1 < L_SEQ) issue_x(step + 1);  // hide HBM latency under MFMAs

    f32x4 acc0 = {0.f, 0.f, 0.f, 0.f};
    f32x4 acc1 = {0.f, 0.f, 0.f, 0.f};
#pragma unroll
    for (int kk = 0; kk < 16; ++kk) {
      // B-operand: B[q][m] = u[m][32kk+q]; lane: m = m16, q = 8*g4 + i
      int off = m16 * 1024 + (((kk * 64) + g4 * 16) ^ ((m16 & 7) << 4));
      bf16x8 uf = *(const bf16x8*)(uLds + off);
      acc0 = __builtin_amdgcn_mfma_f32_16x16x32_bf16(wfrag[0][kk], uf, acc0, 0, 0, 0);
      acc1 = __builtin_amdgcn_mfma_f32_16x16x32_bf16(wfrag[1][kk], uf, acc1, 0, 0, 0);
    }
    __syncthreads();  // all u reads done -> safe to overwrite u

    // epilogue: D[j][m] -> sigmoid -> global hidden + LDS h for next step
    float h0[4], h1[4];
#pragma unroll
    for (int r = 0; r < 4; ++r) {
      h0[r] = 1.f / (1.f + __expf(-(acc0[r] + biasr[0][r])));
      h1[r] = 1.f / (1.f + __expf(-(acc1[r] + biasr[1][r])));
    }
    // global write: hidden[step][b0+m16][dir*256 + j], j = 32w (+16t) + 4g4 + r
    float* gp = hidden + ((long)step * BATCH + b0 + m16) * HID2 + dir * HDIM + 32 * w + 4 * g4;
    *(float4*)(gp)      = make_float4(h0[0], h0[1], h0[2], h0[3]);
    *(float4*)(gp + 16) = make_float4(h1[0], h1[1], h1[2], h1[3]);
    // LDS h write (bf16, swizzled): u[m16][256 + j]
    {
      int jb0 = 32 * w + 4 * g4;
      bf16x4 v0, v1;
#pragma unroll
      for (int r = 0; r < 4; ++r) { v0[r] = (short)f2bf(h0[r]); v1[r] = (short)f2bf(h1[r]); }
      int off0 = m16 * 1024 + (((256 + jb0) * 2) ^ ((m16 & 7) << 4));
      int off1 = m16 * 1024 + (((256 + jb0 + 16) * 2) ^ ((m16 & 7) << 4));
      *(bf16x4*)(uLds + off0) = v0;
      *(bf16x4*)(uLds + off1) = v1;
    }
    if (step + 1 < L_SEQ) write_x();
    __syncthreads();  // h/x for next step visible
  }
}

// out[lb][t] = hidden[lb][:] . W_out[t][:] + b_out[t]
// One wave per 16-row M-tile; A resident (hidden rows), B streamed from global.
__global__ __launch_bounds__(64) void out_kernel(
    const float* __restrict__ hidden, const float* __restrict__ W_out,
    const float* __restrict__ b_out, float* __restrict__ out) {
  const int m0 = blockIdx.x * 16;
  const int ln = threadIdx.x;
  const int m16 = ln & 15, g4 = ln >> 4;

  bf16x8 a[16];
  const float* hp = hidden + (long)(m0 + m16) * HID2 + g4 * 8;
#pragma unroll
  for (int kk = 0; kk < 16; ++kk) {
    float4 p0 = *(const float4*)(hp + kk * 32);
    float4 p1 = *(const float4*)(hp + kk * 32 + 4);
    float f[8] = {p0.x, p0.y, p0.z, p0.w, p1.x, p1.y, p1.z, p1.w};
    a[kk] = pack8(f);
  }
#pragma unroll
  for (int nt = 0; nt < 4; ++nt) {
    const int trow = nt * 16 + m16;
    const bool valid = trow < TDIM;
    f32x4 acc = {0.f, 0.f, 0.f, 0.f};
    const float* wp = W_out + (long)trow * HID2 + g4 * 8;
#pragma unroll
    for (int kk = 0; kk < 16; ++kk) {
      bf16x8 bf;
      if (valid) {
        float4 p0 = *(const float4*)(wp + kk * 32);
        float4 p1 = *(const float4*)(wp + kk * 32 + 4);
        float f[8] = {p0.x, p0.y, p0.z, p0.w, p1.x, p1.y, p1.z, p1.w};
        bf = pack8(f);
      } else {
#pragma unroll
        for (int i = 0; i < 8; ++i) bf[i] = 0;
      }
      acc = __builtin_amdgcn_mfma_f32_16x16x32_bf16(a[kk], bf, acc, 0, 0, 0);
    }
    if (valid) {
      float bo = b_out[trow];
#pragma unroll
      for (int r = 0; r < 4; ++r)
        out[(long)(m0 + 4 * g4 + r) * TDIM + trow] = acc[r] + bo;
    }
  }
}

extern "C" void kernel_launch(void* const* d_in, const int* in_sizes, int n_in,
                              void* d_out, int out_size, void* d_ws, size_t ws_size,
                              hipStream_t stream) {
  const int*   text  = (const int*)d_in[0];
  const float* emb   = (const float*)d_in[1];
  const float* W_f   = (const float*)d_in[2];
  const float* b_f   = (const float*)d_in[3];
  const float* W_b   = (const float*)d_in[4];
  const float* b_b   = (const float*)d_in[5];
  const float* W_out = (const float*)d_in[6];
  const float* b_out = (const float*)d_in[7];
  float* out    = (float*)d_out;
  float* hidden = out + (long)L_SEQ * BATCH * TDIM;  // second tuple output

  scan_kernel<<<8, 512, 0, stream>>>(text, emb, W_f, b_f, W_b, b_b, hidden);
  out_kernel<<<2048, 64, 0, stream>>>(hidden, W_out, b_out, out);
}

// Round 2
// 582.990 us; speedup vs baseline: 1.2866x; 1.2866x over previous
//
#include <hip/hip_runtime.h>
#include <stdint.h>

#define L_SEQ 512
#define BATCH 64
#define KTOT  512   // E + H
#define TDIM  50
#define HID2  512   // 2*H
#define ROWSTRIDE ((long)BATCH * HID2)  // floats per l-slice of hidden

typedef __attribute__((ext_vector_type(8))) short bf16x8;
typedef __attribute__((ext_vector_type(4))) short bf16x4;
typedef __attribute__((ext_vector_type(4))) float f32x4;

static __device__ __forceinline__ unsigned short f2bf(float f) {
  union { float f; unsigned int u; } v; v.f = f;
  unsigned int r = (v.u + 0x7FFFu + ((v.u >> 16) & 1u)) >> 16;  // RNE
  return (unsigned short)r;
}

static __device__ __forceinline__ bf16x8 pack8(const float* f) {
  bf16x8 r;
#pragma unroll
  for (int i = 0; i < 8; ++i) r[i] = (short)f2bf(f[i]);
  return r;
}

// LDS tile layout (16 rows x 256 k, bf16, 512 B/row):
//   byte = m*512 + ((k*2) ^ ((m&7)<<4))   (T2 XOR swizzle, 16B granular)

// ---------------------------------------------------------------------------
// pre_kernel: P[g][dir*256 + j] = emb[text] . W_dir[j][0:256] + b_dir[j]
// written INTO the hidden output region (scan RMWs it in place).
// dir=1 rows are time-reversed: row l holds x[511-l] . W_b^T (so scan reads
// its own step row s directly).
// ---------------------------------------------------------------------------
__global__ __launch_bounds__(512) void pre_kernel(
    const int* __restrict__ text, const float* __restrict__ emb,
    const float* __restrict__ W_f, const float* __restrict__ b_f,
    const float* __restrict__ W_b, const float* __restrict__ b_b,
    float* __restrict__ hidden) {
  const int blk = blockIdx.x;          // 0..511
  const int dir = blk >> 8;
  const int base = (blk & 255) * 128;  // g-row base (g = l*64 + b)
  const float* W    = dir ? W_b : W_f;
  const float* bias = dir ? b_b : b_f;
  const int tid = threadIdx.x;
  const int w = tid >> 6, ln = tid & 63, m16 = ln & 15, g4 = ln >> 4;

  __shared__ __align__(16) unsigned char xLds[16 * 512];

  // W x-part fragments: wave w owns j-range [w*32, w*32+32), K=256
  bf16x8 wfrag[2][8];
#pragma unroll
  for (int t = 0; t < 2; ++t) {
    const int j0 = w * 32 + t * 16 + m16;
#pragma unroll
    for (int kk = 0; kk < 8; ++kk) {
      const float* p = W + (long)j0 * KTOT + kk * 32 + g4 * 8;
      float4 p0 = *(const float4*)(p);
      float4 p1 = *(const float4*)(p + 4);
      float f[8] = {p0.x, p0.y, p0.z, p0.w, p1.x, p1.y, p1.z, p1.w};
      wfrag[t][kk] = pack8(f);
    }
  }
  float biasr[2][4];
#pragma unroll
  for (int t = 0; t < 2; ++t)
#pragma unroll
    for (int r = 0; r < 4; ++r) biasr[t][r] = bias[w * 32 + t * 16 + 4 * g4 + r];

  const int xm = tid >> 5;          // staged row
  const int e0 = (tid & 31) * 8;    // 8 contiguous f32 per thread

  for (int mt = 0; mt < 8; ++mt) {
    const int g = base + mt * 16 + xm;
    const int l = g >> 6, b = g & 63;
    const int srcl = dir ? (L_SEQ - 1 - l) : l;
    const int tok = text[srcl * BATCH + b];
    const float* xp = emb + (long)tok * 256 + e0;
    float4 a0 = *(const float4*)(xp);
    float4 a1 = *(const float4*)(xp + 4);
    float f[8] = {a0.x, a0.y, a0.z, a0.w, a1.x, a1.y, a1.z, a1.w};
    bf16x8 xv = pack8(f);
    if (mt) __syncthreads();  // prior tile's reads done before overwrite
    *(bf16x8*)(xLds + xm * 512 + ((e0 * 2) ^ ((xm & 7) << 4))) = xv;
    __syncthreads();

    f32x4 acc0 = {0.f, 0.f, 0.f, 0.f};
    f32x4 acc1 = {0.f, 0.f, 0.f, 0.f};
#pragma unroll
    for (int kk = 0; kk < 8; ++kk) {
      bf16x8 uf = *(const bf16x8*)(xLds + m16 * 512 +
                                   (((kk * 64) + g4 * 16) ^ ((m16 & 7) << 4)));
      acc0 = __builtin_amdgcn_mfma_f32_16x16x32_bf16(wfrag[0][kk], uf, acc0, 0, 0, 0);
      acc1 = __builtin_amdgcn_mfma_f32_16x16x32_bf16(wfrag[1][kk], uf, acc1, 0, 0, 0);
    }
    const int gg = base + mt * 16 + m16;
    float* op = hidden + (long)gg * HID2 + dir * 256 + w * 32 + 4 * g4;
    *(float4*)(op)      = make_float4(acc0[0] + biasr[0][0], acc0[1] + biasr[0][1],
                                      acc0[2] + biasr[0][2], acc0[3] + biasr[0][3]);
    *(float4*)(op + 16) = make_float4(acc1[0] + biasr[1][0], acc1[1] + biasr[1][1],
                                      acc1[2] + biasr[1][2], acc1[3] + biasr[1][3]);
  }
}

// ---------------------------------------------------------------------------
// scan_kernel: h' = sigmoid(P + W_h . h), K=256, in-place RMW on hidden.
// 8 WGs (2 dirs x 4 batch-groups), 4 waves, 4 output tiles/wave.
// Double-buffered h in LDS -> ONE raw barrier per step, lgkmcnt-only drain.
// ---------------------------------------------------------------------------
__global__ __launch_bounds__(256, 1) void scan_kernel(
    const float* __restrict__ W_f, const float* __restrict__ W_b,
    float* __restrict__ hidden) {
  const int wg  = blockIdx.x;     // 0..7
  const int dir = wg >> 2;
  const int b0  = (wg & 3) * 16;
  const int tid = threadIdx.x;
  const int w = tid >> 6, ln = tid & 63, m16 = ln & 15, g4 = ln >> 4;
  const float* W = dir ? W_b : W_f;

  __shared__ __align__(16) unsigned char hLds[2][16 * 512];

  // W h-part fragments: wave w owns j-range [w*64, w*64+64)
  bf16x8 wfrag[4][8];
#pragma unroll
  for (int t = 0; t < 4; ++t) {
    const int j0 = w * 64 + t * 16 + m16;
#pragma unroll
    for (int kk = 0; kk < 8; ++kk) {
      const float* p = W + (long)j0 * KTOT + 256 + kk * 32 + g4 * 8;
      float4 p0 = *(const float4*)(p);
      float4 p1 = *(const float4*)(p + 4);
      float f[8] = {p0.x, p0.y, p0.z, p0.w, p1.x, p1.y, p1.z, p1.w};
      wfrag[t][kk] = pack8(f);
    }
  }

  // zero h buffer 0 (256 threads x 32 B)
  *(f32x4*)(hLds[0] + tid * 32)      = f32x4{0.f, 0.f, 0.f, 0.f};
  *(f32x4*)(hLds[0] + tid * 32 + 16) = f32x4{0.f, 0.f, 0.f, 0.f};

  // per-lane column offset into a hidden l-slice (same addr for P read & h write)
  const long roff = (long)(b0 + m16) * HID2 + dir * 256 + w * 64 + 4 * g4;

  f32x4 pf[4];
#pragma unroll
  for (int t = 0; t < 4; ++t) pf[t] = *(const f32x4*)(hidden + roff + t * 16);

  __syncthreads();

  for (int s = 0; s < L_SEQ; ++s) {
    const int p = s & 1;
    // prefetch next step's P (off critical path; clamped dummy at s=511)
    const long snext = (long)(s + 1 < L_SEQ ? s + 1 : s) * ROWSTRIDE;
    f32x4 nf[4];
#pragma unroll
    for (int t = 0; t < 4; ++t)
      nf[t] = *(const f32x4*)(hidden + snext + roff + t * 16);

    bf16x8 uf[8];
#pragma unroll
    for (int kk = 0; kk < 8; ++kk)
      uf[kk] = *(const bf16x8*)(hLds[p] + m16 * 512 +
                                (((kk * 64) + g4 * 16) ^ ((m16 & 7) << 4)));

    f32x4 acc[4];
#pragma unroll
    for (int t = 0; t < 4; ++t) acc[t] = f32x4{0.f, 0.f, 0.f, 0.f};
#pragma unroll
    for (int kk = 0; kk < 8; ++kk)
#pragma unroll
      for (int t = 0; t < 4; ++t)
        acc[t] = __builtin_amdgcn_mfma_f32_16x16x32_bf16(wfrag[t][kk], uf[kk], acc[t], 0, 0, 0);

    float* gp = hidden + (long)s * ROWSTRIDE + roff;
    unsigned char* wb = hLds[p ^ 1] + m16 * 512;
#pragma unroll
    for (int t = 0; t < 4; ++t) {
      float h[4];
#pragma unroll
      for (int r = 0; r < 4; ++r) {
        const float x = acc[t][r] + pf[t][r];
        h[r] = __builtin_amdgcn_rcpf(1.f + __expf(-x));
      }
      *(float4*)(gp + t * 16) = make_float4(h[0], h[1], h[2], h[3]);
      bf16x4 v;
#pragma unroll
      for (int r = 0; r < 4; ++r) v[r] = (short)f2bf(h[r]);
      const int kbyte = (w * 64 + t * 16 + 4 * g4) * 2;
      *(bf16x4*)(wb + (kbyte ^ ((m16 & 7) << 4))) = v;
    }
#pragma unroll
    for (int t = 0; t < 4; ++t) pf[t] = nf[t];

    // LDS-only drain + raw barrier: global loads/stores stay in flight
    asm volatile("s_waitcnt lgkmcnt(0)" ::: "memory");
    __builtin_amdgcn_s_barrier();
    asm volatile("" ::: "memory");
  }
}

// ---------------------------------------------------------------------------
// out[lb][t] = hidden[lb][:] . W_out[t][:] + b_out[t]
// ---------------------------------------------------------------------------
__global__ __launch_bounds__(64) void out_kernel(
    const float* __restrict__ hidden, const float* __restrict__ W_out,
    const float* __restrict__ b_out, float* __restrict__ out) {
  const int m0 = blockIdx.x * 16;
  const int ln = threadIdx.x;
  const int m16 = ln & 15, g4 = ln >> 4;

  bf16x8 a[16];
  const float* hp = hidden + (long)(m0 + m16) * HID2 + g4 * 8;
#pragma unroll
  for (int kk = 0; kk < 16; ++kk) {
    float4 p0 = *(const float4*)(hp + kk * 32);
    float4 p1 = *(const float4*)(hp + kk * 32 + 4);
    float f[8] = {p0.x, p0.y, p0.z, p0.w, p1.x, p1.y, p1.z, p1.w};
    a[kk] = pack8(f);
  }
#pragma unroll
  for (int nt = 0; nt < 4; ++nt) {
    const int trow = nt * 16 + m16;
    const bool valid = trow < TDIM;
    f32x4 acc = {0.f, 0.f, 0.f, 0.f};
    const float* wp = W_out + (long)trow * HID2 + g4 * 8;
#pragma unroll
    for (int kk = 0; kk < 16; ++kk) {
      bf16x8 bf;
      if (valid) {
        float4 p0 = *(const float4*)(wp + kk * 32);
        float4 p1 = *(const float4*)(wp + kk * 32 + 4);
        float f[8] = {p0.x, p0.y, p0.z, p0.w, p1.x, p1.y, p1.z, p1.w};
        bf = pack8(f);
      } else {
#pragma unroll
        for (int i = 0; i < 8; ++i) bf[i] = 0;
      }
      acc = __builtin_amdgcn_mfma_f32_16x16x32_bf16(a[kk], bf, acc, 0, 0, 0);
    }
    if (valid) {
      float bo = b_out[trow];
#pragma unroll
      for (int r = 0; r < 4; ++r)
        out[(long)(m0 + 4 * g4 + r) * TDIM + trow] = acc[r] + bo;
    }
  }
}

extern "C" void kernel_launch(void* const* d_in, const int* in_sizes, int n_in,
                              void* d_out, int out_size, void* d_ws, size_t ws_size,
                              hipStream_t stream) {
  const int*   text  = (const int*)d_in[0];
  const float* emb   = (const float*)d_in[1];
  const float* W_f   = (const float*)d_in[2];
  const float* b_f   = (const float*)d_in[3];
  const float* W_b   = (const float*)d_in[4];
  const float* b_b   = (const float*)d_in[5];
  const float* W_out = (const float*)d_in[6];
  const float* b_out = (const float*)d_in[7];
  float* out    = (float*)d_out;
  float* hidden = out + (long)L_SEQ * BATCH * TDIM;  // second tuple output

  pre_kernel<<<512, 512, 0, stream>>>(text, emb, W_f, b_f, W_b, b_b, hidden);
  scan_kernel<<<8, 256, 0, stream>>>(W_f, W_b, hidden);
  out_kernel<<<2048, 64, 0, stream>>>(hidden, W_out, b_out, out);
}